// Round 2
// baseline (240.565 us; speedup 1.0000x reference)
//
#include <hip/hip_runtime.h>
#include <hip/hip_bf16.h>
#include <math.h>

// Problem constants
#define B_  1024
#define N_  32
#define D_  512
#define EPS_ 1e-5f

typedef __attribute__((ext_vector_type(8))) short bf16x8;   // 8 bf16 = 4 VGPRs
typedef __attribute__((ext_vector_type(4))) float f32x4;
using bf16 = __hip_bfloat16;
typedef unsigned int u32;
typedef const u32 __attribute__((address_space(1)))* gp_t;
typedef u32 __attribute__((address_space(3)))* sp_t;

// async global->LDS, 16 B per lane, lds dest = uniform base + lane*16
static __device__ __forceinline__ void gload16(const void* g, void* s) {
  __builtin_amdgcn_global_load_lds((gp_t)g, (sp_t)s, 16, 0, 0);
}

static __device__ __forceinline__ unsigned short f2bf(float f) {
  union { float f; u32 u; } c; c.f = f;
  u32 r = c.u + 0x7fff + ((c.u >> 16) & 1);   // RNE
  return (unsigned short)(r >> 16);
}
static __device__ __forceinline__ float bf2f(unsigned short h) {
  union { u32 u; float f; } c; c.u = ((u32)h) << 16;
  return c.f;
}

// ---------------------------------------------------------------------------
// Transpose + cast: in [mat][R][C] f32 -> out [mat][C][R] bf16
// ---------------------------------------------------------------------------
__global__ __launch_bounds__(256) void transpose_cast_kernel(
    const float* __restrict__ in, bf16* __restrict__ out, int R, int C) {
  __shared__ float tile[32][33];
  const size_t mat = (size_t)blockIdx.z * (size_t)R * (size_t)C;
  const float* inp = in + mat;
  bf16* outp = out + mat;
  const int c0 = blockIdx.x * 32, r0 = blockIdx.y * 32;
  const int tx = threadIdx.x & 31, ty = threadIdx.x >> 5;   // 32 x 8
#pragma unroll
  for (int i = 0; i < 4; ++i) {
    int r = ty + i * 8;
    tile[r][tx] = inp[(size_t)(r0 + r) * C + (c0 + tx)];
  }
  __syncthreads();
#pragma unroll
  for (int i = 0; i < 4; ++i) {
    int r = ty + i * 8;
    outp[(size_t)(c0 + r) * R + (r0 + tx)] = __float2bfloat16(tile[tx][r]);
  }
}

// ---------------------------------------------------------------------------
// mix + LN: x[m][b][d] = LN_d( sum_k A[p[k], m] * z[b,k,d] )*g+b  (bf16)
// also writes inverse permutation inv[b][v].
// ---------------------------------------------------------------------------
__global__ __launch_bounds__(256) void mix_ln_kernel(
    const float* __restrict__ z, const int* __restrict__ idx,
    const float* __restrict__ A, const float* __restrict__ gamma,
    const float* __restrict__ beta, bf16* __restrict__ x_ws,
    int* __restrict__ inv_ws) {
  __shared__ float As[32][32];      // As[k][n] = A[p[k]][n]
  __shared__ int   p[32];
  __shared__ float red1[4][32];
  __shared__ float red2[4][32];
  __shared__ float meanS[32];
  __shared__ float rstdS[32];

  const int b = blockIdx.x;
  const int t = threadIdx.x;
  const int lane = t & 63, wid = t >> 6;

  if (t < 32) {
    int v = idx[b * 32 + t];
    p[t] = v;
    inv_ws[b * 32 + v] = t;
  }
  __syncthreads();
  for (int i = t; i < 1024; i += 256) {
    int k = i >> 5, n = i & 31;
    As[k][n] = A[p[k] * 32 + n];
  }
  __syncthreads();

  const int d0 = t, d1 = t + 256;
  const float* zb = z + (size_t)b * (N_ * D_);
  float acc0[32], acc1[32];
#pragma unroll
  for (int n = 0; n < 32; ++n) { acc0[n] = 0.f; acc1[n] = 0.f; }

  for (int k = 0; k < 32; ++k) {
    float z0 = zb[k * D_ + d0];
    float z1 = zb[k * D_ + d1];
#pragma unroll
    for (int c = 0; c < 8; ++c) {
      float4 a4 = *(const float4*)&As[k][c * 4];
      acc0[c * 4 + 0] = fmaf(a4.x, z0, acc0[c * 4 + 0]);
      acc1[c * 4 + 0] = fmaf(a4.x, z1, acc1[c * 4 + 0]);
      acc0[c * 4 + 1] = fmaf(a4.y, z0, acc0[c * 4 + 1]);
      acc1[c * 4 + 1] = fmaf(a4.y, z1, acc1[c * 4 + 1]);
      acc0[c * 4 + 2] = fmaf(a4.z, z0, acc0[c * 4 + 2]);
      acc1[c * 4 + 2] = fmaf(a4.z, z1, acc1[c * 4 + 2]);
      acc0[c * 4 + 3] = fmaf(a4.w, z0, acc0[c * 4 + 3]);
      acc1[c * 4 + 3] = fmaf(a4.w, z1, acc1[c * 4 + 3]);
    }
  }

#pragma unroll
  for (int n = 0; n < 32; ++n) {
    float v1 = acc0[n] + acc1[n];
    float v2 = acc0[n] * acc0[n] + acc1[n] * acc1[n];
#pragma unroll
    for (int mk = 1; mk < 64; mk <<= 1) {
      v1 += __shfl_xor(v1, mk);
      v2 += __shfl_xor(v2, mk);
    }
    if (lane == 0) { red1[wid][n] = v1; red2[wid][n] = v2; }
  }
  __syncthreads();
  if (t < 32) {
    float S1 = red1[0][t] + red1[1][t] + red1[2][t] + red1[3][t];
    float S2 = red2[0][t] + red2[1][t] + red2[2][t] + red2[3][t];
    float mean = S1 * (1.f / D_);
    float var  = S2 * (1.f / D_) - mean * mean;
    meanS[t] = mean;
    rstdS[t] = rsqrtf(var + EPS_);
  }
  __syncthreads();

  const float g0 = gamma[d0], g1 = gamma[d1];
  const float be0 = beta[d0], be1 = beta[d1];
#pragma unroll
  for (int n = 0; n < 32; ++n) {
    float mn = meanS[n], rs = rstdS[n];
    float x0 = (acc0[n] - mn) * rs * g0 + be0;
    float x1 = (acc1[n] - mn) * rs * g1 + be1;
    size_t base = ((size_t)n * B_ + b) * D_;
    x_ws[base + d0] = __float2bfloat16(x0);
    x_ws[base + d1] = __float2bfloat16(x1);
  }
}

// ---------------------------------------------------------------------------
// Shared GEMM core: 128x128 tile, BK=32, 4 waves (2x2), 16x16x32 bf16 MFMA,
// global_load_lds(16B) staging with source-preswizzled slot XOR (both-sides).
// A rows -> C rows, B rows -> C cols.  Both operands [rows][K] bf16.
// ---------------------------------------------------------------------------
template <int Kd, int KSTEPS>
static __device__ __forceinline__ void gemm_core(
    const bf16* __restrict__ Ag, const bf16* __restrict__ Bg,
    short* Asb, short* Bsb, f32x4 (&acc)[4][4], int t) {
  const int lane = t & 63, wid = t >> 6;
  const int llo = lane & 15, lhi = lane >> 4;
  const int wr = wid >> 1, wc = wid & 1;

  // staging: 512 chunks of 16B per tile; wave w covers chunks [w*128, w*128+128)
  const int ch0 = wid * 128 + lane;
  const int ch1 = ch0 + 64;
  const int r0 = ch0 >> 2, s0 = ((ch0 ^ r0) & 3) * 8;   // slot ^= row&3 preswizzle
  const int r1 = ch1 >> 2, s1 = ((ch1 ^ r1) & 3) * 8;
  const bf16* a0 = Ag + (size_t)r0 * Kd + s0;
  const bf16* a1 = Ag + (size_t)r1 * Kd + s1;
  const bf16* b0 = Bg + (size_t)r0 * Kd + s0;
  const bf16* b1p = Bg + (size_t)r1 * Kd + s1;
  short* da = Asb + wid * 1024;   // per-wave uniform LDS bases (shorts)
  short* db = Bsb + wid * 1024;

  // read-side XOR: slot read = lhi ^ (row&3); row&3 == llo&3 for all frags
  const int xs = ((lhi ^ llo) & 3) * 8;
  int aoff[4], boff[4];
#pragma unroll
  for (int i = 0; i < 4; ++i) {
    aoff[i] = (wr * 64 + i * 16 + llo) * 32 + xs;
    boff[i] = (wc * 64 + i * 16 + llo) * 32 + xs;
  }

  for (int ks = 0; ks < KSTEPS; ++ks) {
    const int kb = ks * 32;
    if (ks) __syncthreads();             // all reads of prev tile done
    gload16(a0 + kb, da);
    gload16(a1 + kb, da + 512);
    gload16(b0 + kb, db);
    gload16(b1p + kb, db + 512);
    __syncthreads();                     // vmcnt(0) drain -> tile visible
    bf16x8 av[4], bv[4];
#pragma unroll
    for (int i = 0; i < 4; ++i) av[i] = *(const bf16x8*)&Asb[aoff[i]];
#pragma unroll
    for (int j = 0; j < 4; ++j) bv[j] = *(const bf16x8*)&Bsb[boff[j]];
#pragma unroll
    for (int i = 0; i < 4; ++i)
#pragma unroll
      for (int j = 0; j < 4; ++j)
        acc[i][j] = __builtin_amdgcn_mfma_f32_16x16x32_bf16(av[i], bv[j], acc[i][j], 0, 0, 0);
  }
}

// ---------------------------------------------------------------------------
// GEMM1 (swapped): C[h][b] = W1t[h][:] . X[b][:]  (K=512), ELU+bias, store
// H[b][h] as packed bf16x4 (rows of C are contiguous in H's h-axis).
// grid 2048 = 32 m * 8 hb * 8 bb, XCD-swizzled.
// ---------------------------------------------------------------------------
__global__ __launch_bounds__(256) void gemm1_kernel(
    const bf16* __restrict__ X,    // [32][1024][512]
    const bf16* __restrict__ W1t,  // [32][1024][512]
    const float* __restrict__ b1,  // [32][1024]
    bf16* __restrict__ Hout) {     // [32][1024][1024]
  __shared__ short Asb[4096];
  __shared__ short Bsb[4096];

  const int bid = blockIdx.x;
  const int swz = (bid & 7) * 256 + (bid >> 3);   // nwg=2048, bijective
  const int m  = swz >> 6;
  const int r_ = swz & 63;
  const int hb = r_ >> 3, bb = r_ & 7;

  const int t = threadIdx.x;
  const int lane = t & 63, wid = t >> 6;
  const int llo = lane & 15, lhi = lane >> 4;
  const int wr = wid >> 1, wc = wid & 1;

  const bf16* Ag = W1t + (size_t)m * (1024 * 512) + (size_t)(hb * 128) * 512;
  const bf16* Bg = X   + (size_t)m * (1024 * 512) + (size_t)(bb * 128) * 512;

  const f32x4 fzero = {0.f, 0.f, 0.f, 0.f};
  f32x4 acc[4][4];
#pragma unroll
  for (int i = 0; i < 4; ++i)
#pragma unroll
    for (int j = 0; j < 4; ++j) acc[i][j] = fzero;

  gemm_core<512, 16>(Ag, Bg, Asb, Bsb, acc, t);

  bf16* Hm = Hout + (size_t)m * (1024 * 1024);
  const float* b1m = b1 + m * 1024;
#pragma unroll
  for (int i = 0; i < 4; ++i) {
    const int h0 = hb * 128 + wr * 64 + i * 16 + lhi * 4;
    const float4 bi = *(const float4*)&b1m[h0];
#pragma unroll
    for (int j = 0; j < 4; ++j) {
      const int b_ = bb * 128 + wc * 64 + j * 16 + llo;
      float v0 = acc[i][j][0] + bi.x;
      float v1 = acc[i][j][1] + bi.y;
      float v2 = acc[i][j][2] + bi.z;
      float v3 = acc[i][j][3] + bi.w;
      v0 = v0 > 0.f ? v0 : expm1f(v0);
      v1 = v1 > 0.f ? v1 : expm1f(v1);
      v2 = v2 > 0.f ? v2 : expm1f(v2);
      v3 = v3 > 0.f ? v3 : expm1f(v3);
      ushort4 pk;
      pk.x = f2bf(v0); pk.y = f2bf(v1); pk.z = f2bf(v2); pk.w = f2bf(v3);
      *(ushort4*)&Hm[(size_t)b_ * 1024 + h0] = pk;
    }
  }
}

// ---------------------------------------------------------------------------
// GEMM2 (swapped): C[d][b] = W2t[d][:] . H[b][:]  (K=1024); out[b][inv[b][m]][d]
// = C + b2 + x  via float4 stores (rows of C contiguous in d-axis).
// grid 1024 = 32 m * 4 db * 8 bb, XCD-swizzled (same m->XCD map as gemm1).
// ---------------------------------------------------------------------------
__global__ __launch_bounds__(256) void gemm2_kernel(
    const bf16* __restrict__ Hin,  // [32][1024][1024]
    const bf16* __restrict__ W2t,  // [32][512][1024]
    const float* __restrict__ b2,  // [32][512]
    const bf16* __restrict__ Xb,   // [32][1024][512]
    const int* __restrict__ inv,   // [1024][32]
    float* __restrict__ out) {     // [1024][32][512]
  __shared__ short Asb[4096];
  __shared__ short Bsb[4096];

  const int bid = blockIdx.x;
  const int swz = (bid & 7) * 128 + (bid >> 3);   // nwg=1024, bijective
  const int m  = swz >> 5;
  const int r_ = swz & 31;
  const int db_ = r_ >> 3, bb = r_ & 7;

  const int t = threadIdx.x;
  const int lane = t & 63, wid = t >> 6;
  const int llo = lane & 15, lhi = lane >> 4;
  const int wr = wid >> 1, wc = wid & 1;

  const bf16* Ag = W2t + (size_t)m * (512 * 1024) + (size_t)(db_ * 128) * 1024;
  const bf16* Bg = Hin + (size_t)m * (1024 * 1024) + (size_t)(bb * 128) * 1024;

  const f32x4 fzero = {0.f, 0.f, 0.f, 0.f};
  f32x4 acc[4][4];
#pragma unroll
  for (int i = 0; i < 4; ++i)
#pragma unroll
    for (int j = 0; j < 4; ++j) acc[i][j] = fzero;

  gemm_core<1024, 32>(Ag, Bg, Asb, Bsb, acc, t);

  const float* b2m = b2 + m * 512;
  const bf16* Xm = Xb + (size_t)m * (1024 * 512);
#pragma unroll
  for (int j = 0; j < 4; ++j) {
    const int b_ = bb * 128 + wc * 64 + j * 16 + llo;
    const int n_out = inv[b_ * 32 + m];
    float* orow = out + ((size_t)b_ * 32 + n_out) * 512;
    const bf16* xrow = Xm + (size_t)b_ * 512;
#pragma unroll
    for (int i = 0; i < 4; ++i) {
      const int d0 = db_ * 128 + wr * 64 + i * 16 + lhi * 4;
      const float4 bi = *(const float4*)&b2m[d0];
      const ushort4 xr = *(const ushort4*)&xrow[d0];
      float4 v;
      v.x = acc[i][j][0] + bi.x + bf2f(xr.x);
      v.y = acc[i][j][1] + bi.y + bf2f(xr.y);
      v.z = acc[i][j][2] + bi.z + bf2f(xr.z);
      v.w = acc[i][j][3] + bi.w + bf2f(xr.w);
      *(float4*)&orow[d0] = v;
    }
  }
}

// ---------------------------------------------------------------------------
extern "C" void kernel_launch(void* const* d_in, const int* in_sizes, int n_in,
                              void* d_out, int out_size, void* d_ws, size_t ws_size,
                              hipStream_t stream) {
  const float* z     = (const float*)d_in[0];
  const int*   idx   = (const int*)d_in[1];
  const float* A     = (const float*)d_in[2];
  const float* W1    = (const float*)d_in[3];
  const float* b1    = (const float*)d_in[4];
  const float* W2    = (const float*)d_in[5];
  const float* b2    = (const float*)d_in[6];
  const float* gamma = (const float*)d_in[7];
  const float* beta  = (const float*)d_in[8];
  float* out = (float*)d_out;
  char* ws = (char*)d_ws;

  const size_t OFF_X   = 0;           // bf16 [32][1024][512]  : 32 MiB
  const size_t OFF_H   = 33554432;    // bf16 [32][1024][1024] : 64 MiB
  const size_t OFF_W1T = 100663296;   // bf16 [32][1024][512]  : 32 MiB
  const size_t OFF_W2T = 134217728;   // bf16 [32][512][1024]  : 32 MiB
  const size_t OFF_INV = 167772160;   // int  [1024][32]       : 128 KiB
  const size_t NEED    = 167903232;
  if (ws_size < NEED) return;

  bf16* Xb  = (bf16*)(ws + OFF_X);
  bf16* Hb  = (bf16*)(ws + OFF_H);
  bf16* W1t = (bf16*)(ws + OFF_W1T);
  bf16* W2t = (bf16*)(ws + OFF_W2T);
  int*  inv = (int*)(ws + OFF_INV);

  // W1 [32][512][1024] -> W1t [32][1024][512]
  transpose_cast_kernel<<<dim3(32, 16, 32), 256, 0, stream>>>(W1, W1t, 512, 1024);
  // W2 [32][1024][512] -> W2t [32][512][1024]
  transpose_cast_kernel<<<dim3(16, 32, 32), 256, 0, stream>>>(W2, W2t, 1024, 512);

  mix_ln_kernel<<<dim3(B_), 256, 0, stream>>>(z, idx, A, gamma, beta, Xb, inv);

  gemm1_kernel<<<dim3(2048), 256, 0, stream>>>(Xb, W1t, b1, Hb);
  gemm2_kernel<<<dim3(1024), 256, 0, stream>>>(Hb, W2t, b2, Xb, inv, out);
}

// Round 3
// 231.095 us; speedup vs baseline: 1.0410x; 1.0410x over previous
//
#include <hip/hip_runtime.h>
#include <hip/hip_bf16.h>
#include <math.h>

// Problem constants
#define B_  1024
#define N_  32
#define D_  512
#define EPS_ 1e-5f

typedef __attribute__((ext_vector_type(8))) short bf16x8;   // 8 bf16 = 4 VGPRs
typedef __attribute__((ext_vector_type(4))) float f32x4;
using bf16 = __hip_bfloat16;
typedef unsigned int u32;
typedef const u32 __attribute__((address_space(1)))* gp_t;
typedef u32 __attribute__((address_space(3)))* sp_t;

// async global->LDS, 16 B per lane, lds dest = uniform base + lane*16
static __device__ __forceinline__ void gload16(const void* g, void* s) {
  __builtin_amdgcn_global_load_lds((gp_t)g, (sp_t)s, 16, 0, 0);
}

static __device__ __forceinline__ unsigned short f2bf(float f) {
  union { float f; u32 u; } c; c.f = f;
  u32 r = c.u + 0x7fff + ((c.u >> 16) & 1);   // RNE
  return (unsigned short)(r >> 16);
}
static __device__ __forceinline__ float bf2f(unsigned short h) {
  union { u32 u; float f; } c; c.u = ((u32)h) << 16;
  return c.f;
}

// ---------------------------------------------------------------------------
// Transpose + cast: in [mat][R][C] f32 -> out [mat][C][R] bf16
// ---------------------------------------------------------------------------
__global__ __launch_bounds__(256) void transpose_cast_kernel(
    const float* __restrict__ in, bf16* __restrict__ out, int R, int C) {
  __shared__ float tile[32][33];
  const size_t mat = (size_t)blockIdx.z * (size_t)R * (size_t)C;
  const float* inp = in + mat;
  bf16* outp = out + mat;
  const int c0 = blockIdx.x * 32, r0 = blockIdx.y * 32;
  const int tx = threadIdx.x & 31, ty = threadIdx.x >> 5;   // 32 x 8
#pragma unroll
  for (int i = 0; i < 4; ++i) {
    int r = ty + i * 8;
    tile[r][tx] = inp[(size_t)(r0 + r) * C + (c0 + tx)];
  }
  __syncthreads();
#pragma unroll
  for (int i = 0; i < 4; ++i) {
    int r = ty + i * 8;
    outp[(size_t)(c0 + r) * R + (r0 + tx)] = __float2bfloat16(tile[tx][r]);
  }
}

// ---------------------------------------------------------------------------
// mix + LN: x[m][b][d] = LN_d( sum_k A[p[k], m] * z[b,k,d] )*g+b  (bf16)
// also writes inverse permutation inv[b][v].
// ---------------------------------------------------------------------------
__global__ __launch_bounds__(256) void mix_ln_kernel(
    const float* __restrict__ z, const int* __restrict__ idx,
    const float* __restrict__ A, const float* __restrict__ gamma,
    const float* __restrict__ beta, bf16* __restrict__ x_ws,
    int* __restrict__ inv_ws) {
  __shared__ float As[32][32];      // As[k][n] = A[p[k]][n]
  __shared__ int   p[32];
  __shared__ float red1[4][32];
  __shared__ float red2[4][32];
  __shared__ float meanS[32];
  __shared__ float rstdS[32];

  const int b = blockIdx.x;
  const int t = threadIdx.x;
  const int lane = t & 63, wid = t >> 6;

  if (t < 32) {
    int v = idx[b * 32 + t];
    p[t] = v;
    inv_ws[b * 32 + v] = t;
  }
  __syncthreads();
  for (int i = t; i < 1024; i += 256) {
    int k = i >> 5, n = i & 31;
    As[k][n] = A[p[k] * 32 + n];
  }
  __syncthreads();

  const int d0 = t, d1 = t + 256;
  const float* zb = z + (size_t)b * (N_ * D_);
  float acc0[32], acc1[32];
#pragma unroll
  for (int n = 0; n < 32; ++n) { acc0[n] = 0.f; acc1[n] = 0.f; }

  for (int k = 0; k < 32; ++k) {
    float z0 = zb[k * D_ + d0];
    float z1 = zb[k * D_ + d1];
#pragma unroll
    for (int c = 0; c < 8; ++c) {
      float4 a4 = *(const float4*)&As[k][c * 4];
      acc0[c * 4 + 0] = fmaf(a4.x, z0, acc0[c * 4 + 0]);
      acc1[c * 4 + 0] = fmaf(a4.x, z1, acc1[c * 4 + 0]);
      acc0[c * 4 + 1] = fmaf(a4.y, z0, acc0[c * 4 + 1]);
      acc1[c * 4 + 1] = fmaf(a4.y, z1, acc1[c * 4 + 1]);
      acc0[c * 4 + 2] = fmaf(a4.z, z0, acc0[c * 4 + 2]);
      acc1[c * 4 + 2] = fmaf(a4.z, z1, acc1[c * 4 + 2]);
      acc0[c * 4 + 3] = fmaf(a4.w, z0, acc0[c * 4 + 3]);
      acc1[c * 4 + 3] = fmaf(a4.w, z1, acc1[c * 4 + 3]);
    }
  }

#pragma unroll
  for (int n = 0; n < 32; ++n) {
    float v1 = acc0[n] + acc1[n];
    float v2 = acc0[n] * acc0[n] + acc1[n] * acc1[n];
#pragma unroll
    for (int mk = 1; mk < 64; mk <<= 1) {
      v1 += __shfl_xor(v1, mk);
      v2 += __shfl_xor(v2, mk);
    }
    if (lane == 0) { red1[wid][n] = v1; red2[wid][n] = v2; }
  }
  __syncthreads();
  if (t < 32) {
    float S1 = red1[0][t] + red1[1][t] + red1[2][t] + red1[3][t];
    float S2 = red2[0][t] + red2[1][t] + red2[2][t] + red2[3][t];
    float mean = S1 * (1.f / D_);
    float var  = S2 * (1.f / D_) - mean * mean;
    meanS[t] = mean;
    rstdS[t] = rsqrtf(var + EPS_);
  }
  __syncthreads();

  const float g0 = gamma[d0], g1 = gamma[d1];
  const float be0 = beta[d0], be1 = beta[d1];
#pragma unroll
  for (int n = 0; n < 32; ++n) {
    float mn = meanS[n], rs = rstdS[n];
    float x0 = (acc0[n] - mn) * rs * g0 + be0;
    float x1 = (acc1[n] - mn) * rs * g1 + be1;
    size_t base = ((size_t)n * B_ + b) * D_;
    x_ws[base + d0] = __float2bfloat16(x0);
    x_ws[base + d1] = __float2bfloat16(x1);
  }
}

// ---------------------------------------------------------------------------
// GEMM core, 2-phase double-buffered (T3 minimum recipe):
//   prologue stage(0); barrier;
//   for ks: stage(ks+1 -> other buf); ds_read(cur); MFMA; barrier;
// LDS map (shorts): A buf c = smem + c*4096, B buf c = smem + 8192 + c*4096.
// 128x128 tile, BK=32, 4 waves (2x2), mfma_f32_16x16x32_bf16.
// Staging slot XOR-preswizzled on the global source; same XOR on ds_read.
// ---------------------------------------------------------------------------
template <int Kd, int KSTEPS>
static __device__ __forceinline__ void gemm_core(
    const bf16* __restrict__ Ag, const bf16* __restrict__ Bg,
    short* smem, f32x4 (&acc)[4][4], int t) {
  const int lane = t & 63, wid = t >> 6;
  const int llo = lane & 15, lhi = lane >> 4;
  const int wr = wid >> 1, wc = wid & 1;

  // staging: 512 chunks of 16B per operand tile; wave w: chunks [w*128, +128)
  const int ch0 = wid * 128 + lane;
  const int ch1 = ch0 + 64;
  const int r0 = ch0 >> 2, s0 = ((ch0 ^ r0) & 3) * 8;   // slot ^= row&3
  const int r1 = ch1 >> 2, s1 = ((ch1 ^ r1) & 3) * 8;
  const bf16* a0 = Ag + (size_t)r0 * Kd + s0;
  const bf16* a1 = Ag + (size_t)r1 * Kd + s1;
  const bf16* b0 = Bg + (size_t)r0 * Kd + s0;
  const bf16* b1p = Bg + (size_t)r1 * Kd + s1;
  const int dof = wid * 1024;        // wave's uniform dest offset (shorts)

  // read-side XOR: physical slot = lhi ^ (row&3), row&3 == llo&3
  const int xs = ((lhi ^ llo) & 3) * 8;
  int aoff[4], boff[4];
#pragma unroll
  for (int i = 0; i < 4; ++i) {
    aoff[i] = (wr * 64 + i * 16 + llo) * 32 + xs;
    boff[i] = (wc * 64 + i * 16 + llo) * 32 + xs;
  }

  // prologue: stage tile 0 into buf 0
  gload16(a0, smem + dof);
  gload16(a1, smem + dof + 512);
  gload16(b0, smem + 8192 + dof);
  gload16(b1p, smem + 8192 + dof + 512);
  __syncthreads();

#pragma unroll 2
  for (int ks = 0; ks < KSTEPS; ++ks) {
    const int cur = ks & 1;
    if (ks + 1 < KSTEPS) {               // issue next-tile loads FIRST
      const int kb = (ks + 1) * 32;
      const int nb = (cur ^ 1) * 4096;
      gload16(a0 + kb, smem + nb + dof);
      gload16(a1 + kb, smem + nb + dof + 512);
      gload16(b0 + kb, smem + 8192 + nb + dof);
      gload16(b1p + kb, smem + 8192 + nb + dof + 512);
    }
    const short* Ac = smem + cur * 4096;
    const short* Bc = smem + 8192 + cur * 4096;
    bf16x8 av[4], bv[4];
#pragma unroll
    for (int i = 0; i < 4; ++i) av[i] = *(const bf16x8*)&Ac[aoff[i]];
#pragma unroll
    for (int j = 0; j < 4; ++j) bv[j] = *(const bf16x8*)&Bc[boff[j]];
#pragma unroll
    for (int i = 0; i < 4; ++i)
#pragma unroll
      for (int j = 0; j < 4; ++j)
        acc[i][j] = __builtin_amdgcn_mfma_f32_16x16x32_bf16(av[i], bv[j], acc[i][j], 0, 0, 0);
    if (ks + 1 < KSTEPS) __syncthreads();   // drains vmcnt -> next buf ready
  }
}

// ---------------------------------------------------------------------------
// GEMM1 (swapped): C[h][b] = W1t[h][:] . X[b][:] (K=512), bias+ELU.
// Epilogue: per-wave 64x64 tile staged to private LDS (XOR-swizzled), read
// back row-wise -> 16B coalesced stores into H[b][h] (full sectors, no RMW).
// grid 2048 = 32 m * 8 hb * 8 bb, XCD-swizzled.
// ---------------------------------------------------------------------------
__global__ __launch_bounds__(256) void gemm1_kernel(
    const bf16* __restrict__ X,    // [32][1024][512]
    const bf16* __restrict__ W1t,  // [32][1024][512]
    const float* __restrict__ b1,  // [32][1024]
    bf16* __restrict__ Hout) {     // [32][1024][1024]
  __shared__ short smem[16384];    // 32 KB: dbuf A (16KB) + dbuf B (16KB)

  const int bid = blockIdx.x;
  const int swz = (bid & 7) * 256 + (bid >> 3);   // nwg=2048, bijective
  const int m  = swz >> 6;
  const int r_ = swz & 63;
  const int hb = r_ >> 3, bb = r_ & 7;

  const int t = threadIdx.x;
  const int lane = t & 63, wid = t >> 6;
  const int llo = lane & 15, lhi = lane >> 4;
  const int wr = wid >> 1, wc = wid & 1;

  const bf16* Ag = W1t + (size_t)m * (1024 * 512) + (size_t)(hb * 128) * 512;
  const bf16* Bg = X   + (size_t)m * (1024 * 512) + (size_t)(bb * 128) * 512;

  const f32x4 fzero = {0.f, 0.f, 0.f, 0.f};
  f32x4 acc[4][4];
#pragma unroll
  for (int i = 0; i < 4; ++i)
#pragma unroll
    for (int j = 0; j < 4; ++j) acc[i][j] = fzero;

  gemm_core<512, 16>(Ag, Bg, smem, acc, t);

  // ---- epilogue: bias + ELU, stage to LDS [b_loc][h_loc] (bf16, swizzled)
  __syncthreads();                       // staging bufs now reusable
  char* eps = (char*)(smem + wid * 4096);   // 8 KB per wave = 64x64 bf16
  const float* b1m = b1 + m * 1024;
#pragma unroll
  for (int i = 0; i < 4; ++i) {
    const int hl = i * 16 + lhi * 4;
    const float4 bi = *(const float4*)&b1m[hb * 128 + wr * 64 + hl];
#pragma unroll
    for (int j = 0; j < 4; ++j) {
      const int bl = j * 16 + llo;
      float v0 = acc[i][j][0] + bi.x;
      float v1 = acc[i][j][1] + bi.y;
      float v2 = acc[i][j][2] + bi.z;
      float v3 = acc[i][j][3] + bi.w;
      v0 = v0 > 0.f ? v0 : expm1f(v0);
      v1 = v1 > 0.f ? v1 : expm1f(v1);
      v2 = v2 > 0.f ? v2 : expm1f(v2);
      v3 = v3 > 0.f ? v3 : expm1f(v3);
      ushort4 pk;
      pk.x = f2bf(v0); pk.y = f2bf(v1); pk.z = f2bf(v2); pk.w = f2bf(v3);
      const int byte = (bl * 128 + hl * 2) ^ ((bl & 7) << 4);
      *(ushort4*)(eps + byte) = pk;
    }
  }
  // wave-private region: no barrier needed (lgkmcnt ordering within wave)
  bf16* Hm = Hout + (size_t)m * (1024 * 1024);
  const int c8 = lane & 7, bl8 = lane >> 3;
#pragma unroll
  for (int r = 0; r < 8; ++r) {
    const int bl = r * 8 + bl8;
    const int byte = (bl * 128 + c8 * 16) ^ ((bl & 7) << 4);
    bf16x8 vv = *(const bf16x8*)(eps + byte);
    const int b_g = bb * 128 + wc * 64 + bl;
    const int h_g = hb * 128 + wr * 64 + c8 * 8;
    *(bf16x8*)&Hm[(size_t)b_g * 1024 + h_g] = vv;
  }
}

// ---------------------------------------------------------------------------
// GEMM2 (swapped): C[d][b] = W2t[d][:] . H[b][:] (K=1024);
// out[b][inv[b][m]][d] = C + b2 + x via float4 stores.
// grid 1024 = 32 m * 4 db * 8 bb, XCD-swizzled.
// ---------------------------------------------------------------------------
__global__ __launch_bounds__(256) void gemm2_kernel(
    const bf16* __restrict__ Hin,  // [32][1024][1024]
    const bf16* __restrict__ W2t,  // [32][512][1024]
    const float* __restrict__ b2,  // [32][512]
    const bf16* __restrict__ Xb,   // [32][1024][512]
    const int* __restrict__ inv,   // [1024][32]
    float* __restrict__ out) {     // [1024][32][512]
  __shared__ short smem[16384];

  const int bid = blockIdx.x;
  const int swz = (bid & 7) * 128 + (bid >> 3);   // nwg=1024, bijective
  const int m  = swz >> 5;
  const int r_ = swz & 31;
  const int db_ = r_ >> 3, bb = r_ & 7;

  const int t = threadIdx.x;
  const int lane = t & 63, wid = t >> 6;
  const int llo = lane & 15, lhi = lane >> 4;
  const int wr = wid >> 1, wc = wid & 1;

  const bf16* Ag = W2t + (size_t)m * (512 * 1024) + (size_t)(db_ * 128) * 1024;
  const bf16* Bg = Hin + (size_t)m * (1024 * 1024) + (size_t)(bb * 128) * 1024;

  const f32x4 fzero = {0.f, 0.f, 0.f, 0.f};
  f32x4 acc[4][4];
#pragma unroll
  for (int i = 0; i < 4; ++i)
#pragma unroll
    for (int j = 0; j < 4; ++j) acc[i][j] = fzero;

  gemm_core<1024, 32>(Ag, Bg, smem, acc, t);

  const float* b2m = b2 + m * 512;
  const bf16* Xm = Xb + (size_t)m * (1024 * 512);
#pragma unroll
  for (int j = 0; j < 4; ++j) {
    const int b_ = bb * 128 + wc * 64 + j * 16 + llo;
    const int n_out = inv[b_ * 32 + m];
    float* orow = out + ((size_t)b_ * 32 + n_out) * 512;
    const bf16* xrow = Xm + (size_t)b_ * 512;
#pragma unroll
    for (int i = 0; i < 4; ++i) {
      const int d0 = db_ * 128 + wr * 64 + i * 16 + lhi * 4;
      const float4 bi = *(const float4*)&b2m[d0];
      const ushort4 xr = *(const ushort4*)&xrow[d0];
      float4 v;
      v.x = acc[i][j][0] + bi.x + bf2f(xr.x);
      v.y = acc[i][j][1] + bi.y + bf2f(xr.y);
      v.z = acc[i][j][2] + bi.z + bf2f(xr.z);
      v.w = acc[i][j][3] + bi.w + bf2f(xr.w);
      *(float4*)&orow[d0] = v;
    }
  }
}

// ---------------------------------------------------------------------------
extern "C" void kernel_launch(void* const* d_in, const int* in_sizes, int n_in,
                              void* d_out, int out_size, void* d_ws, size_t ws_size,
                              hipStream_t stream) {
  const float* z     = (const float*)d_in[0];
  const int*   idx   = (const int*)d_in[1];
  const float* A     = (const float*)d_in[2];
  const float* W1    = (const float*)d_in[3];
  const float* b1    = (const float*)d_in[4];
  const float* W2    = (const float*)d_in[5];
  const float* b2    = (const float*)d_in[6];
  const float* gamma = (const float*)d_in[7];
  const float* beta  = (const float*)d_in[8];
  float* out = (float*)d_out;
  char* ws = (char*)d_ws;

  const size_t OFF_X   = 0;           // bf16 [32][1024][512]  : 32 MiB
  const size_t OFF_H   = 33554432;    // bf16 [32][1024][1024] : 64 MiB
  const size_t OFF_W1T = 100663296;   // bf16 [32][1024][512]  : 32 MiB
  const size_t OFF_W2T = 134217728;   // bf16 [32][512][1024]  : 32 MiB
  const size_t OFF_INV = 167772160;   // int  [1024][32]       : 128 KiB
  const size_t NEED    = 167903232;
  if (ws_size < NEED) return;

  bf16* Xb  = (bf16*)(ws + OFF_X);
  bf16* Hb  = (bf16*)(ws + OFF_H);
  bf16* W1t = (bf16*)(ws + OFF_W1T);
  bf16* W2t = (bf16*)(ws + OFF_W2T);
  int*  inv = (int*)(ws + OFF_INV);

  // W1 [32][512][1024] -> W1t [32][1024][512]
  transpose_cast_kernel<<<dim3(32, 16, 32), 256, 0, stream>>>(W1, W1t, 512, 1024);
  // W2 [32][1024][512] -> W2t [32][512][1024]
  transpose_cast_kernel<<<dim3(16, 32, 32), 256, 0, stream>>>(W2, W2t, 1024, 512);

  mix_ln_kernel<<<dim3(B_), 256, 0, stream>>>(z, idx, A, gamma, beta, Xb, inv);

  gemm1_kernel<<<dim3(2048), 256, 0, stream>>>(Xb, W1t, b1, Hb);
  gemm2_kernel<<<dim3(1024), 256, 0, stream>>>(Hb, W2t, b2, Xb, inv, out);
}

// Round 4
// 202.795 us; speedup vs baseline: 1.1863x; 1.1396x over previous
//
#include <hip/hip_runtime.h>
#include <hip/hip_bf16.h>
#include <math.h>

// Problem constants
#define B_  1024
#define N_  32
#define D_  512
#define EPS_ 1e-5f

typedef __attribute__((ext_vector_type(8))) short bf16x8;   // 8 bf16 = 4 VGPRs
typedef __attribute__((ext_vector_type(4))) float f32x4;
using bf16 = __hip_bfloat16;
typedef unsigned int u32;
typedef const u32 __attribute__((address_space(1)))* gp_t;
typedef u32 __attribute__((address_space(3)))* sp_t;

// async global->LDS, 16 B per lane, lds dest = wave-uniform base + lane*16
static __device__ __forceinline__ void gload16(const void* g, void* s) {
  __builtin_amdgcn_global_load_lds((gp_t)g, (sp_t)s, 16, 0, 0);
}
static __device__ __forceinline__ void bar() {
  asm volatile("s_barrier" ::: "memory");
}

static __device__ __forceinline__ unsigned short f2bf(float f) {
  union { float f; u32 u; } c; c.f = f;
  u32 r = c.u + 0x7fff + ((c.u >> 16) & 1);   // RNE
  return (unsigned short)(r >> 16);
}
static __device__ __forceinline__ float bf2f(unsigned short h) {
  union { u32 u; float f; } c; c.u = ((u32)h) << 16;
  return c.f;
}

// ---------------------------------------------------------------------------
// Transpose + cast: in [mat][R][C] f32 -> out [mat][C][R] bf16. 64x64 tiles.
// float4 loads, bf16 LDS tile, 16B bf16x8 coalesced stores.
// ---------------------------------------------------------------------------
__global__ __launch_bounds__(256) void transpose_cast_kernel(
    const float* __restrict__ in, bf16* __restrict__ out, int R, int C) {
  __shared__ unsigned short tile[64][65];
  const size_t mat = (size_t)blockIdx.z * (size_t)R * (size_t)C;
  const float* inp = in + mat;
  bf16* outp = out + mat;
  const int c0 = blockIdx.x * 64, r0 = blockIdx.y * 64;
  const int tr = threadIdx.x >> 4;          // 0..15
  const int tc = (threadIdx.x & 15) * 4;    // 0,4,..,60
#pragma unroll
  for (int i = 0; i < 4; ++i) {
    const int r = tr + i * 16;
    float4 v = *(const float4*)&inp[(size_t)(r0 + r) * C + c0 + tc];
    tile[r][tc + 0] = f2bf(v.x);
    tile[r][tc + 1] = f2bf(v.y);
    tile[r][tc + 2] = f2bf(v.z);
    tile[r][tc + 3] = f2bf(v.w);
  }
  __syncthreads();
#pragma unroll
  for (int i = 0; i < 2; ++i) {
    const int chunk = i * 256 + threadIdx.x;
    const int c = chunk >> 3, r8 = (chunk & 7) * 8;
    union { bf16x8 v; unsigned short u[8]; } pk;
#pragma unroll
    for (int k = 0; k < 8; ++k) pk.u[k] = tile[r8 + k][c];
    *(bf16x8*)&outp[(size_t)(c0 + c) * R + r0 + r8] = pk.v;
  }
}

// ---------------------------------------------------------------------------
// mix + LN: x[m][b][d] = LN_d( sum_k A[p[k], m] * z[b,k,d] )*g+b  (bf16)
// also writes inverse permutation inv[b][v].
// ---------------------------------------------------------------------------
__global__ __launch_bounds__(256) void mix_ln_kernel(
    const float* __restrict__ z, const int* __restrict__ idx,
    const float* __restrict__ A, const float* __restrict__ gamma,
    const float* __restrict__ beta, bf16* __restrict__ x_ws,
    int* __restrict__ inv_ws) {
  __shared__ float As[32][32];      // As[k][n] = A[p[k]][n]
  __shared__ int   p[32];
  __shared__ float red1[4][32];
  __shared__ float red2[4][32];
  __shared__ float meanS[32];
  __shared__ float rstdS[32];

  const int b = blockIdx.x;
  const int t = threadIdx.x;
  const int lane = t & 63, wid = t >> 6;

  if (t < 32) {
    int v = idx[b * 32 + t];
    p[t] = v;
    inv_ws[b * 32 + v] = t;
  }
  __syncthreads();
  for (int i = t; i < 1024; i += 256) {
    int k = i >> 5, n = i & 31;
    As[k][n] = A[p[k] * 32 + n];
  }
  __syncthreads();

  const int d0 = t, d1 = t + 256;
  const float* zb = z + (size_t)b * (N_ * D_);
  float acc0[32], acc1[32];
#pragma unroll
  for (int n = 0; n < 32; ++n) { acc0[n] = 0.f; acc1[n] = 0.f; }

  for (int k = 0; k < 32; ++k) {
    float z0 = zb[k * D_ + d0];
    float z1 = zb[k * D_ + d1];
#pragma unroll
    for (int c = 0; c < 8; ++c) {
      float4 a4 = *(const float4*)&As[k][c * 4];
      acc0[c * 4 + 0] = fmaf(a4.x, z0, acc0[c * 4 + 0]);
      acc1[c * 4 + 0] = fmaf(a4.x, z1, acc1[c * 4 + 0]);
      acc0[c * 4 + 1] = fmaf(a4.y, z0, acc0[c * 4 + 1]);
      acc1[c * 4 + 1] = fmaf(a4.y, z1, acc1[c * 4 + 1]);
      acc0[c * 4 + 2] = fmaf(a4.z, z0, acc0[c * 4 + 2]);
      acc1[c * 4 + 2] = fmaf(a4.z, z1, acc1[c * 4 + 2]);
      acc0[c * 4 + 3] = fmaf(a4.w, z0, acc0[c * 4 + 3]);
      acc1[c * 4 + 3] = fmaf(a4.w, z1, acc1[c * 4 + 3]);
    }
  }

#pragma unroll
  for (int n = 0; n < 32; ++n) {
    float v1 = acc0[n] + acc1[n];
    float v2 = acc0[n] * acc0[n] + acc1[n] * acc1[n];
#pragma unroll
    for (int mk = 1; mk < 64; mk <<= 1) {
      v1 += __shfl_xor(v1, mk);
      v2 += __shfl_xor(v2, mk);
    }
    if (lane == 0) { red1[wid][n] = v1; red2[wid][n] = v2; }
  }
  __syncthreads();
  if (t < 32) {
    float S1 = red1[0][t] + red1[1][t] + red1[2][t] + red1[3][t];
    float S2 = red2[0][t] + red2[1][t] + red2[2][t] + red2[3][t];
    float mean = S1 * (1.f / D_);
    float var  = S2 * (1.f / D_) - mean * mean;
    meanS[t] = mean;
    rstdS[t] = rsqrtf(var + EPS_);
  }
  __syncthreads();

  const float g0 = gamma[d0], g1 = gamma[d1];
  const float be0 = beta[d0], be1 = beta[d1];
#pragma unroll
  for (int n = 0; n < 32; ++n) {
    float mn = meanS[n], rs = rstdS[n];
    float x0 = (acc0[n] - mn) * rs * g0 + be0;
    float x1 = (acc1[n] - mn) * rs * g1 + be1;
    size_t base = ((size_t)n * B_ + b) * D_;
    x_ws[base + d0] = __float2bfloat16(x0);
    x_ws[base + d1] = __float2bfloat16(x1);
  }
}

// ---------------------------------------------------------------------------
// 8-phase 256x256 GEMM core (T3+T4+T5). BK=64, 512 threads = 8 waves (4Mx2N
// inside each 128x128 quadrant: wave w -> rows (w&3)*32, cols (w>>2)*64).
// LDS 128KB: A = 2 parity x 2 half(128x64) = 64KB at [0,64K); B at [64K,128K).
// Per phase: 12 ds_read_b128 + 1 half-tile stage (2 gload16) + barrier +
// 16 MFMA (setprio-wrapped) + barrier. vmcnt(4) once per subtile (counted,
// never 0 mid-loop). Slot-XOR swizzle pre-applied on global source.
// ---------------------------------------------------------------------------
#define STG_A(P, H, S) do {                                                   \
    const bf16* g_ = Ag + (size_t)((H) * 128) * KD + (S) * 64 + soff;         \
    gload16(g_, Alds + (P) * 32768 + (H) * 16384 + dof);                      \
    gload16(g_ + (size_t)64 * KD, Alds + (P) * 32768 + (H) * 16384 + 8192 + dof); \
  } while (0)
#define STG_B(P, H, S) do {                                                   \
    const bf16* g_ = Bg + (size_t)((H) * 128) * KD + (S) * 64 + soff;         \
    gload16(g_, Blds + (P) * 32768 + (H) * 16384 + dof);                      \
    gload16(g_ + (size_t)64 * KD, Blds + (P) * 32768 + (H) * 16384 + 8192 + dof); \
  } while (0)

#define PHASE(P, QR, QC, STAGE_STMT, GEND_STMT)                               \
  {                                                                           \
    const char* Ab = Alds + (P) * 32768 + (QR) * 16384;                       \
    const char* Bb = Blds + (P) * 32768 + (QC) * 16384;                       \
    bf16x8 av[2][2], bv[4][2];                                                \
    _Pragma("unroll")                                                         \
    for (int fi = 0; fi < 2; ++fi) {                                          \
      av[fi][0] = *(const bf16x8*)(Ab + raA + fi * 2048 + j16);               \
      av[fi][1] = *(const bf16x8*)(Ab + raA + fi * 2048 + (j16 ^ 64));        \
    }                                                                         \
    _Pragma("unroll")                                                         \
    for (int fj = 0; fj < 4; ++fj) {                                          \
      bv[fj][0] = *(const bf16x8*)(Bb + raB + fj * 2048 + j16);               \
      bv[fj][1] = *(const bf16x8*)(Bb + raB + fj * 2048 + (j16 ^ 64));        \
    }                                                                         \
    STAGE_STMT;                                                               \
    bar();                                                                    \
    __builtin_amdgcn_s_setprio(1);                                            \
    _Pragma("unroll")                                                         \
    for (int fi = 0; fi < 2; ++fi)                                            \
      _Pragma("unroll")                                                       \
      for (int fj = 0; fj < 4; ++fj) {                                        \
        acc[QR][QC][fi][fj] = __builtin_amdgcn_mfma_f32_16x16x32_bf16(        \
            av[fi][0], bv[fj][0], acc[QR][QC][fi][fj], 0, 0, 0);              \
        acc[QR][QC][fi][fj] = __builtin_amdgcn_mfma_f32_16x16x32_bf16(        \
            av[fi][1], bv[fj][1], acc[QR][QC][fi][fj], 0, 0, 0);              \
      }                                                                       \
    __builtin_amdgcn_s_setprio(0);                                            \
    GEND_STMT;                                                                \
    bar();                                                                    \
  }

#define VMC4() asm volatile("s_waitcnt vmcnt(4)" ::: "memory")
#define VMC0() asm volatile("s_waitcnt vmcnt(0)" ::: "memory")

template <int KD, int NS>
static __device__ __forceinline__ void gemm8_core(
    const bf16* __restrict__ Ag, const bf16* __restrict__ Bg,
    char* __restrict__ Alds, char* __restrict__ Blds,
    f32x4 (&acc)[2][2][2][4], const int t) {
  const int lane = t & 63, wid = t >> 6;
  const int llo = lane & 15, lhi = lane >> 4;
  const int raA = ((wid & 3) * 32 + llo) * 128;        // A row byte base
  const int raB = ((wid >> 2) * 64 + llo) * 128;       // B row byte base
  const int j16 = (lhi ^ (llo & 7)) * 16;              // swizzled k-slot
  const int soff = (t >> 3) * KD + ((t ^ (t >> 3)) & 7) * 8;  // stage src
  const int dof = wid * 1024;                          // stage LDS dest

  // prologue: subtile 0 complete + Ah0(1), Bh0(1)  (12 loads, keep 4 in flight)
  STG_A(0, 0, 0); STG_B(0, 0, 0); STG_A(0, 1, 0); STG_B(0, 1, 0);
  STG_A(1, 0, 1); STG_B(1, 0, 1);
  VMC4();
  bar();

#pragma unroll 1
  for (int it = 0; it < NS / 2; ++it) {
    const int s0 = 2 * it;             // parity 0
    PHASE(0, 0, 0, { if (s0 + 1 < NS) STG_A(1, 1, s0 + 1); }, {})
    PHASE(0, 0, 1, { if (s0 + 1 < NS) STG_B(1, 1, s0 + 1); }, {})
    PHASE(0, 1, 0, { if (s0 + 2 < NS) STG_A(0, 0, s0 + 2); }, {})
    PHASE(0, 1, 1, { if (s0 + 2 < NS) STG_B(0, 0, s0 + 2); },
          { if (s0 + 2 < NS) VMC4(); else VMC0(); })
    const int s1 = 2 * it + 1;         // parity 1
    PHASE(1, 0, 0, { if (s1 + 1 < NS) STG_A(0, 1, s1 + 1); }, {})
    PHASE(1, 0, 1, { if (s1 + 1 < NS) STG_B(0, 1, s1 + 1); }, {})
    PHASE(1, 1, 0, { if (s1 + 2 < NS) STG_A(1, 0, s1 + 2); }, {})
    PHASE(1, 1, 1, { if (s1 + 2 < NS) STG_B(1, 0, s1 + 2); },
          { if (s1 + 2 < NS) VMC4(); else VMC0(); })
  }
}

// ---------------------------------------------------------------------------
// GEMM1: C[h][b] = W1t[h][:] . X[b][:] (K=512), bias+ELU -> H[b][h] bf16.
// 256x256 tile; epilogue transposes block tile through the freed 128KB LDS
// for 16B coalesced H stores. grid 512 = 32m * 4hb * 4bb, XCD-swizzled.
// ---------------------------------------------------------------------------
__global__ __launch_bounds__(512, 2) void gemm1_kernel(
    const bf16* __restrict__ X,    // [32][1024][512]
    const bf16* __restrict__ W1t,  // [32][1024][512]
    const float* __restrict__ b1,  // [32][1024]
    bf16* __restrict__ Hout) {     // [32][1024][1024]
  extern __shared__ char lds[];
  char* Alds = lds;
  char* Blds = lds + 65536;

  const int bid = blockIdx.x;
  const int swz = (bid & 7) * 64 + (bid >> 3);   // nwg=512, bijective
  const int m  = swz >> 4;
  const int r_ = swz & 15;
  const int hb = r_ >> 2, bb = r_ & 3;

  const int t = threadIdx.x;
  const int lane = t & 63, wid = t >> 6;
  const int llo = lane & 15, lhi = lane >> 4;

  const bf16* Ag = W1t + (size_t)m * (1024 * 512) + (size_t)(hb * 256) * 512;
  const bf16* Bg = X   + (size_t)m * (1024 * 512) + (size_t)(bb * 256) * 512;

  const f32x4 fzero = {0.f, 0.f, 0.f, 0.f};
  f32x4 acc[2][2][2][4];
#pragma unroll
  for (int a = 0; a < 2; ++a)
#pragma unroll
    for (int b = 0; b < 2; ++b)
#pragma unroll
      for (int c = 0; c < 2; ++c)
#pragma unroll
        for (int d = 0; d < 4; ++d) acc[a][b][c][d] = fzero;

  gemm8_core<512, 8>(Ag, Bg, Alds, Blds, acc, t);

  // ---- epilogue: bias + ELU -> LDS [256 b][256 h] bf16 (swizzled) -> 16B st
  const float* b1m = b1 + m * 1024 + hb * 256;
#pragma unroll
  for (int qr = 0; qr < 2; ++qr)
#pragma unroll
    for (int fi = 0; fi < 2; ++fi) {
      const int h_loc = qr * 128 + (wid & 3) * 32 + fi * 16 + lhi * 4;
      const float4 bi = *(const float4*)&b1m[h_loc];
#pragma unroll
      for (int qc = 0; qc < 2; ++qc)
#pragma unroll
        for (int fj = 0; fj < 4; ++fj) {
          const int b_loc = qc * 128 + (wid >> 2) * 64 + fj * 16 + llo;
          float v0 = acc[qr][qc][fi][fj][0] + bi.x;
          float v1 = acc[qr][qc][fi][fj][1] + bi.y;
          float v2 = acc[qr][qc][fi][fj][2] + bi.z;
          float v3 = acc[qr][qc][fi][fj][3] + bi.w;
          v0 = v0 > 0.f ? v0 : expm1f(v0);
          v1 = v1 > 0.f ? v1 : expm1f(v1);
          v2 = v2 > 0.f ? v2 : expm1f(v2);
          v3 = v3 > 0.f ? v3 : expm1f(v3);
          ushort4 pk;
          pk.x = f2bf(v0); pk.y = f2bf(v1); pk.z = f2bf(v2); pk.w = f2bf(v3);
          const int byte = (b_loc * 512 + h_loc * 2) ^ ((b_loc & 7) << 4);
          *(ushort4*)(lds + byte) = pk;
        }
    }
  __syncthreads();
  bf16* Hm = Hout + (size_t)m * (1024 * 1024);
  const int b0 = bb * 256, h0 = hb * 256;
#pragma unroll
  for (int r = 0; r < 16; ++r) {
    const int chunk = r * 512 + t;
    const int bl = chunk >> 5, hc = chunk & 31;
    const int byte = (bl * 512 + hc * 16) ^ ((bl & 7) << 4);
    bf16x8 v = *(const bf16x8*)(lds + byte);
    *(bf16x8*)&Hm[(size_t)(b0 + bl) * 1024 + h0 + hc * 8] = v;
  }
}

// ---------------------------------------------------------------------------
// GEMM2: C[d][b] = W2t[d][:] . H[b][:] (K=1024);
// out[b][inv[b][m]][d] = C + b2 + x via float4 stores.
// grid 256 = 32m * 2db * 4bb, XCD-swizzled (same m->XCD map as gemm1).
// ---------------------------------------------------------------------------
__global__ __launch_bounds__(512, 2) void gemm2_kernel(
    const bf16* __restrict__ Hin,  // [32][1024][1024]
    const bf16* __restrict__ W2t,  // [32][512][1024]
    const float* __restrict__ b2,  // [32][512]
    const bf16* __restrict__ Xb,   // [32][1024][512]
    const int* __restrict__ inv,   // [1024][32]
    float* __restrict__ out) {     // [1024][32][512]
  extern __shared__ char lds[];
  char* Alds = lds;
  char* Blds = lds + 65536;

  const int bid = blockIdx.x;
  const int swz = (bid & 7) * 32 + (bid >> 3);   // nwg=256, bijective
  const int m  = swz >> 3;
  const int r_ = swz & 7;
  const int db_ = r_ >> 2, bb = r_ & 3;

  const int t = threadIdx.x;
  const int lane = t & 63, wid = t >> 6;
  const int llo = lane & 15, lhi = lane >> 4;

  const bf16* Ag = W2t + (size_t)m * (512 * 1024) + (size_t)(db_ * 256) * 1024;
  const bf16* Bg = Hin + (size_t)m * (1024 * 1024) + (size_t)(bb * 256) * 1024;

  const f32x4 fzero = {0.f, 0.f, 0.f, 0.f};
  f32x4 acc[2][2][2][4];
#pragma unroll
  for (int a = 0; a < 2; ++a)
#pragma unroll
    for (int b = 0; b < 2; ++b)
#pragma unroll
      for (int c = 0; c < 2; ++c)
#pragma unroll
        for (int d = 0; d < 4; ++d) acc[a][b][c][d] = fzero;

  gemm8_core<1024, 16>(Ag, Bg, Alds, Blds, acc, t);

  const float* b2m = b2 + m * 512;
  const bf16* Xm = Xb + (size_t)m * (1024 * 512);
#pragma unroll
  for (int qc = 0; qc < 2; ++qc)
#pragma unroll
    for (int fj = 0; fj < 4; ++fj) {
      const int b_ = bb * 256 + qc * 128 + (wid >> 2) * 64 + fj * 16 + llo;
      const int n_out = inv[b_ * 32 + m];
      float* orow = out + ((size_t)b_ * 32 + n_out) * 512;
      const bf16* xrow = Xm + (size_t)b_ * 512;
#pragma unroll
      for (int qr = 0; qr < 2; ++qr)
#pragma unroll
        for (int fi = 0; fi < 2; ++fi) {
          const int d0 = db_ * 256 + qr * 128 + (wid & 3) * 32 + fi * 16 + lhi * 4;
          const float4 bi = *(const float4*)&b2m[d0];
          const ushort4 xr = *(const ushort4*)&xrow[d0];
          float4 v;
          v.x = acc[qr][qc][fi][fj][0] + bi.x + bf2f(xr.x);
          v.y = acc[qr][qc][fi][fj][1] + bi.y + bf2f(xr.y);
          v.z = acc[qr][qc][fi][fj][2] + bi.z + bf2f(xr.z);
          v.w = acc[qr][qc][fi][fj][3] + bi.w + bf2f(xr.w);
          *(float4*)&orow[d0] = v;
        }
    }
}

// ---------------------------------------------------------------------------
extern "C" void kernel_launch(void* const* d_in, const int* in_sizes, int n_in,
                              void* d_out, int out_size, void* d_ws, size_t ws_size,
                              hipStream_t stream) {
  const float* z     = (const float*)d_in[0];
  const int*   idx   = (const int*)d_in[1];
  const float* A     = (const float*)d_in[2];
  const float* W1    = (const float*)d_in[3];
  const float* b1    = (const float*)d_in[4];
  const float* W2    = (const float*)d_in[5];
  const float* b2    = (const float*)d_in[6];
  const float* gamma = (const float*)d_in[7];
  const float* beta  = (const float*)d_in[8];
  float* out = (float*)d_out;
  char* ws = (char*)d_ws;

  const size_t OFF_X   = 0;           // bf16 [32][1024][512]  : 32 MiB
  const size_t OFF_H   = 33554432;    // bf16 [32][1024][1024] : 64 MiB
  const size_t OFF_W1T = 100663296;   // bf16 [32][1024][512]  : 32 MiB
  const size_t OFF_W2T = 134217728;   // bf16 [32][512][1024]  : 32 MiB
  const size_t OFF_INV = 167772160;   // int  [1024][32]       : 128 KiB
  const size_t NEED    = 167903232;
  if (ws_size < NEED) return;

  bf16* Xb  = (bf16*)(ws + OFF_X);
  bf16* Hb  = (bf16*)(ws + OFF_H);
  bf16* W1t = (bf16*)(ws + OFF_W1T);
  bf16* W2t = (bf16*)(ws + OFF_W2T);
  int*  inv = (int*)(ws + OFF_INV);

  // allow 128KB dynamic LDS (idempotent host-side calls; not stream ops)
  hipFuncSetAttribute((const void*)gemm1_kernel,
                      hipFuncAttributeMaxDynamicSharedMemorySize, 131072);
  hipFuncSetAttribute((const void*)gemm2_kernel,
                      hipFuncAttributeMaxDynamicSharedMemorySize, 131072);

  // W1 [32][512][1024] -> W1t [32][1024][512]
  transpose_cast_kernel<<<dim3(16, 8, 32), 256, 0, stream>>>(W1, W1t, 512, 1024);
  // W2 [32][1024][512] -> W2t [32][512][1024]
  transpose_cast_kernel<<<dim3(8, 16, 32), 256, 0, stream>>>(W2, W2t, 1024, 512);

  mix_ln_kernel<<<dim3(B_), 256, 0, stream>>>(z, idx, A, gamma, beta, Xb, inv);

  gemm1_kernel<<<dim3(512), 512, 131072, stream>>>(Xb, W1t, b1, Hb);
  gemm2_kernel<<<dim3(256), 512, 131072, stream>>>(Hb, W2t, b2, Xb, inv, out);
}

// Round 5
// 182.243 us; speedup vs baseline: 1.3200x; 1.1128x over previous
//
#include <hip/hip_runtime.h>
#include <hip/hip_bf16.h>
#include <math.h>

// Problem constants
#define B_  1024
#define N_  32
#define D_  512
#define EPS_ 1e-5f

typedef __attribute__((ext_vector_type(8))) short bf16x8;   // 8 bf16 = 4 VGPRs
typedef __attribute__((ext_vector_type(4))) float f32x4;
using bf16 = __hip_bfloat16;
typedef unsigned int u32;
typedef const u32 __attribute__((address_space(1)))* gp_t;
typedef u32 __attribute__((address_space(3)))* sp_t;

// async global->LDS, 16 B per lane, lds dest = wave-uniform base + lane*16
static __device__ __forceinline__ void gload16(const void* g, void* s) {
  __builtin_amdgcn_global_load_lds((gp_t)g, (sp_t)s, 16, 0, 0);
}
static __device__ __forceinline__ void bar() {
  asm volatile("s_barrier" ::: "memory");
}

static __device__ __forceinline__ unsigned short f2bf(float f) {
  union { float f; u32 u; } c; c.f = f;
  u32 r = c.u + 0x7fff + ((c.u >> 16) & 1);   // RNE
  return (unsigned short)(r >> 16);
}
static __device__ __forceinline__ float bf2f(unsigned short h) {
  union { u32 u; float f; } c; c.u = ((u32)h) << 16;
  return c.f;
}

// ---------------------------------------------------------------------------
// Transpose + cast: in [mat][R][C] f32 -> out [mat][C][R] bf16. 64x64 tiles.
// ---------------------------------------------------------------------------
__global__ __launch_bounds__(256) void transpose_cast_kernel(
    const float* __restrict__ in, bf16* __restrict__ out, int R, int C) {
  __shared__ unsigned short tile[64][65];
  const size_t mat = (size_t)blockIdx.z * (size_t)R * (size_t)C;
  const float* inp = in + mat;
  bf16* outp = out + mat;
  const int c0 = blockIdx.x * 64, r0 = blockIdx.y * 64;
  const int tr = threadIdx.x >> 4;          // 0..15
  const int tc = (threadIdx.x & 15) * 4;    // 0,4,..,60
#pragma unroll
  for (int i = 0; i < 4; ++i) {
    const int r = tr + i * 16;
    float4 v = *(const float4*)&inp[(size_t)(r0 + r) * C + c0 + tc];
    tile[r][tc + 0] = f2bf(v.x);
    tile[r][tc + 1] = f2bf(v.y);
    tile[r][tc + 2] = f2bf(v.z);
    tile[r][tc + 3] = f2bf(v.w);
  }
  __syncthreads();
#pragma unroll
  for (int i = 0; i < 2; ++i) {
    const int chunk = i * 256 + threadIdx.x;
    const int c = chunk >> 3, r8 = (chunk & 7) * 8;
    union { bf16x8 v; unsigned short u[8]; } pk;
#pragma unroll
    for (int k = 0; k < 8; ++k) pk.u[k] = tile[r8 + k][c];
    *(bf16x8*)&outp[(size_t)(c0 + c) * R + r0 + r8] = pk.v;
  }
}

// ---------------------------------------------------------------------------
// mix + LN: x[m][b][d] = LN_d( sum_k A[p[k], m] * z[b,k,d] )*g+b  (bf16)
// also writes inverse permutation inv[b][v].
// ---------------------------------------------------------------------------
__global__ __launch_bounds__(256) void mix_ln_kernel(
    const float* __restrict__ z, const int* __restrict__ idx,
    const float* __restrict__ A, const float* __restrict__ gamma,
    const float* __restrict__ beta, bf16* __restrict__ x_ws,
    int* __restrict__ inv_ws) {
  __shared__ float As[32][32];      // As[k][n] = A[p[k]][n]
  __shared__ int   p[32];
  __shared__ float red1[4][32];
  __shared__ float red2[4][32];
  __shared__ float meanS[32];
  __shared__ float rstdS[32];

  const int b = blockIdx.x;
  const int t = threadIdx.x;
  const int lane = t & 63, wid = t >> 6;

  if (t < 32) {
    int v = idx[b * 32 + t];
    p[t] = v;
    inv_ws[b * 32 + v] = t;
  }
  __syncthreads();
  for (int i = t; i < 1024; i += 256) {
    int k = i >> 5, n = i & 31;
    As[k][n] = A[p[k] * 32 + n];
  }
  __syncthreads();

  const int d0 = t, d1 = t + 256;
  const float* zb = z + (size_t)b * (N_ * D_);
  float acc0[32], acc1[32];
#pragma unroll
  for (int n = 0; n < 32; ++n) { acc0[n] = 0.f; acc1[n] = 0.f; }

  for (int k = 0; k < 32; ++k) {
    float z0 = zb[k * D_ + d0];
    float z1 = zb[k * D_ + d1];
#pragma unroll
    for (int c = 0; c < 8; ++c) {
      float4 a4 = *(const float4*)&As[k][c * 4];
      acc0[c * 4 + 0] = fmaf(a4.x, z0, acc0[c * 4 + 0]);
      acc1[c * 4 + 0] = fmaf(a4.x, z1, acc1[c * 4 + 0]);
      acc0[c * 4 + 1] = fmaf(a4.y, z0, acc0[c * 4 + 1]);
      acc1[c * 4 + 1] = fmaf(a4.y, z1, acc1[c * 4 + 1]);
      acc0[c * 4 + 2] = fmaf(a4.z, z0, acc0[c * 4 + 2]);
      acc1[c * 4 + 2] = fmaf(a4.z, z1, acc1[c * 4 + 2]);
      acc0[c * 4 + 3] = fmaf(a4.w, z0, acc0[c * 4 + 3]);
      acc1[c * 4 + 3] = fmaf(a4.w, z1, acc1[c * 4 + 3]);
    }
  }

#pragma unroll
  for (int n = 0; n < 32; ++n) {
    float v1 = acc0[n] + acc1[n];
    float v2 = acc0[n] * acc0[n] + acc1[n] * acc1[n];
#pragma unroll
    for (int mk = 1; mk < 64; mk <<= 1) {
      v1 += __shfl_xor(v1, mk);
      v2 += __shfl_xor(v2, mk);
    }
    if (lane == 0) { red1[wid][n] = v1; red2[wid][n] = v2; }
  }
  __syncthreads();
  if (t < 32) {
    float S1 = red1[0][t] + red1[1][t] + red1[2][t] + red1[3][t];
    float S2 = red2[0][t] + red2[1][t] + red2[2][t] + red2[3][t];
    float mean = S1 * (1.f / D_);
    float var  = S2 * (1.f / D_) - mean * mean;
    meanS[t] = mean;
    rstdS[t] = rsqrtf(var + EPS_);
  }
  __syncthreads();

  const float g0 = gamma[d0], g1 = gamma[d1];
  const float be0 = beta[d0], be1 = beta[d1];
#pragma unroll
  for (int n = 0; n < 32; ++n) {
    float mn = meanS[n], rs = rstdS[n];
    float x0 = (acc0[n] - mn) * rs * g0 + be0;
    float x1 = (acc1[n] - mn) * rs * g1 + be1;
    size_t base = ((size_t)n * B_ + b) * D_;
    x_ws[base + d0] = __float2bfloat16(x0);
    x_ws[base + d1] = __float2bfloat16(x1);
  }
}

// ---------------------------------------------------------------------------
// 8-phase 256x256 GEMM core (T3+T4+T5) with register-held fragments.
// BK=64, 512 threads = 8 waves; wave w -> A-rows (w&3)*32 (+QR*128),
// B-cols (w>>2)*64 (+QC*128). LDS 128KB: A 2par x 2half(128x64)=64KB, B same.
// Gray phase order per K-subtile: (0,0)->(0,1)->(1,1)->(1,0); A quadrant
// reloaded once (P3), both B quadrants held -> 24 ds_read_b128/subtile/wave
// (was 48). Staging/vmcnt/barrier schedule identical to audited r4 version.
// ---------------------------------------------------------------------------
#define STG_A(P, H, S) do {                                                   \
    const bf16* g_ = Ag + (size_t)((H) * 128) * KD + (S) * 64 + soff;         \
    gload16(g_, Alds + (P) * 32768 + (H) * 16384 + dof);                      \
    gload16(g_ + (size_t)64 * KD, Alds + (P) * 32768 + (H) * 16384 + 8192 + dof); \
  } while (0)
#define STG_B(P, H, S) do {                                                   \
    const bf16* g_ = Bg + (size_t)((H) * 128) * KD + (S) * 64 + soff;         \
    gload16(g_, Blds + (P) * 32768 + (H) * 16384 + dof);                      \
    gload16(g_ + (size_t)64 * KD, Blds + (P) * 32768 + (H) * 16384 + 8192 + dof); \
  } while (0)

#define RD_A(P, H) do {                                                       \
    const char* Ab_ = Alds + (P) * 32768 + (H) * 16384;                       \
    _Pragma("unroll")                                                         \
    for (int fi = 0; fi < 2; ++fi) {                                          \
      av[fi][0] = *(const bf16x8*)(Ab_ + raA + fi * 2048 + j16);              \
      av[fi][1] = *(const bf16x8*)(Ab_ + raA + fi * 2048 + (j16 ^ 64));       \
    }                                                                         \
  } while (0)
#define RD_B(P, H, BV) do {                                                   \
    const char* Bb_ = Blds + (P) * 32768 + (H) * 16384;                       \
    _Pragma("unroll")                                                         \
    for (int fj = 0; fj < 4; ++fj) {                                          \
      BV[fj][0] = *(const bf16x8*)(Bb_ + raB + fj * 2048 + j16);              \
      BV[fj][1] = *(const bf16x8*)(Bb_ + raB + fj * 2048 + (j16 ^ 64));       \
    }                                                                         \
  } while (0)

#define MMA16(QR, QC, BV) do {                                                \
    __builtin_amdgcn_s_setprio(1);                                            \
    _Pragma("unroll")                                                         \
    for (int fi = 0; fi < 2; ++fi)                                            \
      _Pragma("unroll")                                                       \
      for (int fj = 0; fj < 4; ++fj) {                                        \
        acc[QR][QC][fi][fj] = __builtin_amdgcn_mfma_f32_16x16x32_bf16(        \
            av[fi][0], BV[fj][0], acc[QR][QC][fi][fj], 0, 0, 0);              \
        acc[QR][QC][fi][fj] = __builtin_amdgcn_mfma_f32_16x16x32_bf16(        \
            av[fi][1], BV[fj][1], acc[QR][QC][fi][fj], 0, 0, 0);              \
      }                                                                       \
    __builtin_amdgcn_s_setprio(0);                                            \
  } while (0)

#define VMC4() asm volatile("s_waitcnt vmcnt(4)" ::: "memory")
#define VMC0() asm volatile("s_waitcnt vmcnt(0)" ::: "memory")

template <int KD, int NS>
static __device__ __forceinline__ void gemm8_core(
    const bf16* __restrict__ Ag, const bf16* __restrict__ Bg,
    char* __restrict__ Alds, char* __restrict__ Blds,
    f32x4 (&acc)[2][2][2][4], const int t) {
  const int lane = t & 63, wid = t >> 6;
  const int llo = lane & 15, lhi = lane >> 4;
  const int raA = ((wid & 3) * 32 + llo) * 128;        // A row byte base
  const int raB = ((wid >> 2) * 64 + llo) * 128;       // B row byte base
  const int j16 = (lhi ^ (llo & 7)) * 16;              // swizzled k-slot
  const int soff = (t >> 3) * KD + ((t ^ (t >> 3)) & 7) * 8;  // stage src
  const int dof = wid * 1024;                          // stage LDS dest

  bf16x8 av[2][2], bv0[4][2], bv1[4][2];

  // prologue: subtile 0 complete + Ah0(1), Bh0(1)
  STG_A(0, 0, 0); STG_B(0, 0, 0); STG_A(0, 1, 0); STG_B(0, 1, 0);
  STG_A(1, 0, 1); STG_B(1, 0, 1);
  VMC4();
  bar();

#pragma unroll 1
  for (int it = 0; it < NS / 2; ++it) {
    const int s0 = 2 * it;
    // ---- even subtile (parity 0) ----
    RD_A(0, 0); RD_B(0, 0, bv0);
    if (s0 + 1 < NS) STG_A(1, 1, s0 + 1);
    bar(); MMA16(0, 0, bv0); bar();
    RD_B(0, 1, bv1);
    if (s0 + 1 < NS) STG_B(1, 1, s0 + 1);
    bar(); MMA16(0, 1, bv1); bar();
    RD_A(0, 1);
    if (s0 + 2 < NS) STG_A(0, 0, s0 + 2);
    bar(); MMA16(1, 1, bv1); bar();
    if (s0 + 2 < NS) STG_B(0, 0, s0 + 2);
    bar(); MMA16(1, 0, bv0);
    if (s0 + 2 < NS) { VMC4(); } else { VMC0(); }
    bar();
    // ---- odd subtile (parity 1) ----
    const int s1 = s0 + 1;
    RD_A(1, 0); RD_B(1, 0, bv0);
    if (s1 + 1 < NS) STG_A(0, 1, s1 + 1);
    bar(); MMA16(0, 0, bv0); bar();
    RD_B(1, 1, bv1);
    if (s1 + 1 < NS) STG_B(0, 1, s1 + 1);
    bar(); MMA16(0, 1, bv1); bar();
    RD_A(1, 1);
    if (s1 + 2 < NS) STG_A(1, 0, s1 + 2);
    bar(); MMA16(1, 1, bv1); bar();
    if (s1 + 2 < NS) STG_B(1, 0, s1 + 2);
    bar(); MMA16(1, 0, bv0);
    if (s1 + 2 < NS) { VMC4(); } else { VMC0(); }
    bar();
  }
}

// ---------------------------------------------------------------------------
// GEMM1: C[h][b] = W1t[h][:] . X[b][:] (K=512), bias+ELU -> H[b][h] bf16.
// 256x256 tile; epilogue transposes through the freed 128KB LDS for 16B
// coalesced H stores. grid 512 = 32m * 4hb * 4bb, XCD-swizzled.
// ---------------------------------------------------------------------------
__global__ __launch_bounds__(512, 2) void gemm1_kernel(
    const bf16* __restrict__ X,    // [32][1024][512]
    const bf16* __restrict__ W1t,  // [32][1024][512]
    const float* __restrict__ b1,  // [32][1024]
    bf16* __restrict__ Hout) {     // [32][1024][1024]
  extern __shared__ char lds[];
  char* Alds = lds;
  char* Blds = lds + 65536;

  const int bid = blockIdx.x;
  const int swz = (bid & 7) * 64 + (bid >> 3);   // nwg=512, bijective
  const int m  = swz >> 4;
  const int r_ = swz & 15;
  const int hb = r_ >> 2, bb = r_ & 3;

  const int t = threadIdx.x;
  const int lane = t & 63, wid = t >> 6;
  const int llo = lane & 15, lhi = lane >> 4;

  const bf16* Ag = W1t + (size_t)m * (1024 * 512) + (size_t)(hb * 256) * 512;
  const bf16* Bg = X   + (size_t)m * (1024 * 512) + (size_t)(bb * 256) * 512;

  const f32x4 fzero = {0.f, 0.f, 0.f, 0.f};
  f32x4 acc[2][2][2][4];
#pragma unroll
  for (int a = 0; a < 2; ++a)
#pragma unroll
    for (int b = 0; b < 2; ++b)
#pragma unroll
      for (int c = 0; c < 2; ++c)
#pragma unroll
        for (int d = 0; d < 4; ++d) acc[a][b][c][d] = fzero;

  gemm8_core<512, 8>(Ag, Bg, Alds, Blds, acc, t);

  // ---- epilogue: bias + ELU -> LDS [256 b][256 h] bf16 (swizzled) -> 16B st
  const float* b1m = b1 + m * 1024 + hb * 256;
#pragma unroll
  for (int qr = 0; qr < 2; ++qr)
#pragma unroll
    for (int fi = 0; fi < 2; ++fi) {
      const int h_loc = qr * 128 + (wid & 3) * 32 + fi * 16 + lhi * 4;
      const float4 bi = *(const float4*)&b1m[h_loc];
#pragma unroll
      for (int qc = 0; qc < 2; ++qc)
#pragma unroll
        for (int fj = 0; fj < 4; ++fj) {
          const int b_loc = qc * 128 + (wid >> 2) * 64 + fj * 16 + llo;
          float v0 = acc[qr][qc][fi][fj][0] + bi.x;
          float v1 = acc[qr][qc][fi][fj][1] + bi.y;
          float v2 = acc[qr][qc][fi][fj][2] + bi.z;
          float v3 = acc[qr][qc][fi][fj][3] + bi.w;
          v0 = v0 > 0.f ? v0 : __expf(v0) - 1.0f;   // ELU (alpha=1)
          v1 = v1 > 0.f ? v1 : __expf(v1) - 1.0f;
          v2 = v2 > 0.f ? v2 : __expf(v2) - 1.0f;
          v3 = v3 > 0.f ? v3 : __expf(v3) - 1.0f;
          ushort4 pk;
          pk.x = f2bf(v0); pk.y = f2bf(v1); pk.z = f2bf(v2); pk.w = f2bf(v3);
          const int byte = (b_loc * 512 + h_loc * 2) ^ ((b_loc & 7) << 4);
          *(ushort4*)(lds + byte) = pk;
        }
    }
  __syncthreads();
  bf16* Hm = Hout + (size_t)m * (1024 * 1024);
  const int b0 = bb * 256, h0 = hb * 256;
#pragma unroll
  for (int r = 0; r < 16; ++r) {
    const int chunk = r * 512 + t;
    const int bl = chunk >> 5, hc = chunk & 31;
    const int byte = (bl * 512 + hc * 16) ^ ((bl & 7) << 4);
    bf16x8 v = *(const bf16x8*)(lds + byte);
    *(bf16x8*)&Hm[(size_t)(b0 + bl) * 1024 + h0 + hc * 8] = v;
  }
}

// ---------------------------------------------------------------------------
// GEMM2: C[d][b] = W2t[d][:] . H[b][:] (K=1024);
// out[b][inv[b][m]][d] = C + b2 + x via float4 stores.
// grid 256 = 32m * 2db * 4bb, XCD-swizzled.
// ---------------------------------------------------------------------------
__global__ __launch_bounds__(512, 2) void gemm2_kernel(
    const bf16* __restrict__ Hin,  // [32][1024][1024]
    const bf16* __restrict__ W2t,  // [32][512][1024]
    const float* __restrict__ b2,  // [32][512]
    const bf16* __restrict__ Xb,   // [32][1024][512]
    const int* __restrict__ inv,   // [1024][32]
    float* __restrict__ out) {     // [1024][32][512]
  extern __shared__ char lds[];
  char* Alds = lds;
  char* Blds = lds + 65536;

  const int bid = blockIdx.x;
  const int swz = (bid & 7) * 32 + (bid >> 3);   // nwg=256, bijective
  const int m  = swz >> 3;
  const int r_ = swz & 7;
  const int db_ = r_ >> 2, bb = r_ & 3;

  const int t = threadIdx.x;
  const int lane = t & 63, wid = t >> 6;
  const int llo = lane & 15, lhi = lane >> 4;

  const bf16* Ag = W2t + (size_t)m * (512 * 1024) + (size_t)(db_ * 256) * 1024;
  const bf16* Bg = Hin + (size_t)m * (1024 * 1024) + (size_t)(bb * 256) * 1024;

  const f32x4 fzero = {0.f, 0.f, 0.f, 0.f};
  f32x4 acc[2][2][2][4];
#pragma unroll
  for (int a = 0; a < 2; ++a)
#pragma unroll
    for (int b = 0; b < 2; ++b)
#pragma unroll
      for (int c = 0; c < 2; ++c)
#pragma unroll
        for (int d = 0; d < 4; ++d) acc[a][b][c][d] = fzero;

  gemm8_core<1024, 16>(Ag, Bg, Alds, Blds, acc, t);

  const float* b2m = b2 + m * 512;
  const bf16* Xm = Xb + (size_t)m * (1024 * 512);
#pragma unroll
  for (int qc = 0; qc < 2; ++qc)
#pragma unroll
    for (int fj = 0; fj < 4; ++fj) {
      const int b_ = bb * 256 + qc * 128 + (wid >> 2) * 64 + fj * 16 + llo;
      const int n_out = inv[b_ * 32 + m];
      float* orow = out + ((size_t)b_ * 32 + n_out) * 512;
      const bf16* xrow = Xm + (size_t)b_ * 512;
#pragma unroll
      for (int qr = 0; qr < 2; ++qr)
#pragma unroll
        for (int fi = 0; fi < 2; ++fi) {
          const int d0 = db_ * 256 + qr * 128 + (wid & 3) * 32 + fi * 16 + lhi * 4;
          const float4 bi = *(const float4*)&b2m[d0];
          const ushort4 xr = *(const ushort4*)&xrow[d0];
          float4 v;
          v.x = acc[qr][qc][fi][fj][0] + bi.x + bf2f(xr.x);
          v.y = acc[qr][qc][fi][fj][1] + bi.y + bf2f(xr.y);
          v.z = acc[qr][qc][fi][fj][2] + bi.z + bf2f(xr.z);
          v.w = acc[qr][qc][fi][fj][3] + bi.w + bf2f(xr.w);
          *(float4*)&orow[d0] = v;
        }
    }
}

// ---------------------------------------------------------------------------
extern "C" void kernel_launch(void* const* d_in, const int* in_sizes, int n_in,
                              void* d_out, int out_size, void* d_ws, size_t ws_size,
                              hipStream_t stream) {
  const float* z     = (const float*)d_in[0];
  const int*   idx   = (const int*)d_in[1];
  const float* A     = (const float*)d_in[2];
  const float* W1    = (const float*)d_in[3];
  const float* b1    = (const float*)d_in[4];
  const float* W2    = (const float*)d_in[5];
  const float* b2    = (const float*)d_in[6];
  const float* gamma = (const float*)d_in[7];
  const float* beta  = (const float*)d_in[8];
  float* out = (float*)d_out;
  char* ws = (char*)d_ws;

  const size_t OFF_X   = 0;           // bf16 [32][1024][512]  : 32 MiB
  const size_t OFF_H   = 33554432;    // bf16 [32][1024][1024] : 64 MiB
  const size_t OFF_W1T = 100663296;   // bf16 [32][1024][512]  : 32 MiB
  const size_t OFF_W2T = 134217728;   // bf16 [32][512][1024]  : 32 MiB
  const size_t OFF_INV = 167772160;   // int  [1024][32]       : 128 KiB
  const size_t NEED    = 167903232;
  if (ws_size < NEED) return;

  bf16* Xb  = (bf16*)(ws + OFF_X);
  bf16* Hb  = (bf16*)(ws + OFF_H);
  bf16* W1t = (bf16*)(ws + OFF_W1T);
  bf16* W2t = (bf16*)(ws + OFF_W2T);
  int*  inv = (int*)(ws + OFF_INV);

  // allow 128KB dynamic LDS (idempotent host-side calls; not stream ops)
  hipFuncSetAttribute((const void*)gemm1_kernel,
                      hipFuncAttributeMaxDynamicSharedMemorySize, 131072);
  hipFuncSetAttribute((const void*)gemm2_kernel,
                      hipFuncAttributeMaxDynamicSharedMemorySize, 131072);

  // W1 [32][512][1024] -> W1t [32][1024][512]
  transpose_cast_kernel<<<dim3(16, 8, 32), 256, 0, stream>>>(W1, W1t, 512, 1024);
  // W2 [32][1024][512] -> W2t [32][512][1024]
  transpose_cast_kernel<<<dim3(8, 16, 32), 256, 0, stream>>>(W2, W2t, 1024, 512);

  mix_ln_kernel<<<dim3(B_), 256, 0, stream>>>(z, idx, A, gamma, beta, Xb, inv);

  gemm1_kernel<<<dim3(512), 512, 131072, stream>>>(Xb, W1t, b1, Hb);
  gemm2_kernel<<<dim3(256), 512, 131072, stream>>>(Hb, W2t, b2, Xb, inv, out);
}